// Round 9
// baseline (577.388 us; speedup 1.0000x reference)
//
#include <hip/hip_runtime.h>
#include <hip/hip_bf16.h>

// ---------------------------------------------------------------------------
// LinearMoLoraLayer: out = x@W_base^T + b_base + 2.0 * sum_e route[e]*(x@A_e^T)@B_e^T
// R9: gemm8 + XCD-aware bijective swizzle (T1, nwg=512%8==0);
//     gate stack -> single barrier-free gate_fused (direct global MFMA frags,
//     4-wave in-block K-split, LDS reduce + softmax + HW write).
// ---------------------------------------------------------------------------

typedef __attribute__((ext_vector_type(8))) short  bf16x8;
typedef __attribute__((ext_vector_type(4))) float  f32x4;
typedef __attribute__((ext_vector_type(4))) unsigned short us4;
typedef __attribute__((ext_vector_type(4))) float  fl4;

__device__ __forceinline__ unsigned short f2bf(float f) {
  unsigned int u = __float_as_uint(f);
  u += 0x7FFFu + ((u >> 16) & 1u);
  return (unsigned short)(u >> 16);
}
__device__ __forceinline__ void gload16(const void* g, void* l) {
  __builtin_amdgcn_global_load_lds(
      (const __attribute__((address_space(1))) unsigned int*)g,
      (__attribute__((address_space(3))) unsigned int*)l, 16, 0, 0);
}

#define BAR() do { asm volatile("" ::: "memory"); \
                   __builtin_amdgcn_s_barrier();  \
                   asm volatile("" ::: "memory"); } while (0)
#define VMCNT6() asm volatile("s_waitcnt vmcnt(6)" ::: "memory")
#define VMCNT0() asm volatile("s_waitcnt vmcnt(0)" ::: "memory")

// ---- workspace layout (bytes) ---------------------------------------------
#define WS_XBF 0u           // [8192][4096] bf16
#define WS_WBF 67108864u    // [4096][4096] bf16
#define WS_AG  100663296u   // [144][4096]  bf16 (rows 0..7 Wg, 8..135 A, 136..143 zero)
#define WS_U   101842944u   // [4096][128]  bf16 (U[o][e*16+r] = 2*B[e][o][r])
#define WS_HW  102891520u   // [8192][128]  bf16 (hw = h*route)

// ---------------------------------------------------------------------------
// Kernel 1: conversions/packing (unchanged, twice-verified)
// ---------------------------------------------------------------------------
__global__ __launch_bounds__(256) void prep_kernel(
    const float* __restrict__ x, const float* __restrict__ Wb,
    const float* __restrict__ Wg, const float* __restrict__ A,
    const float* __restrict__ B,
    unsigned short* __restrict__ Xbf, unsigned short* __restrict__ Wbf,
    unsigned short* __restrict__ AG, unsigned short* __restrict__ U)
{
  const long N0 = 8388608;
  const long N1 = N0 + 4194304;
  const long N2 = N1 + 139264;
  const long N3 = N2 + 8192;
  const long N4 = N3 + 131072;
  long i = (long)blockIdx.x * blockDim.x + threadIdx.x;
  long stride = (long)gridDim.x * blockDim.x;
  for (; i < N4; i += stride) {
    if (i < N1) {
      const float* s; unsigned short* d; long j;
      if (i < N0) { s = x;  d = Xbf; j = i; }
      else        { s = Wb; d = Wbf; j = i - N0; }
      fl4 v = ((const fl4*)s)[j];
      us4 o; o[0]=f2bf(v[0]); o[1]=f2bf(v[1]); o[2]=f2bf(v[2]); o[3]=f2bf(v[3]);
      ((us4*)d)[j] = o;
    } else if (i < N2) {
      long j = i - N1;
      fl4 v = (j < 8192) ? ((const fl4*)Wg)[j] : ((const fl4*)A)[j - 8192];
      us4 o; o[0]=f2bf(v[0]); o[1]=f2bf(v[1]); o[2]=f2bf(v[2]); o[3]=f2bf(v[3]);
      ((us4*)AG)[j] = o;
    } else if (i < N3) {
      long j = i - N2;
      us4 z = (us4)0;
      ((us4*)(AG + 136*4096))[j] = z;
    } else {
      long j = i - N3;
      long o = j >> 5;
      long c4 = j & 31;
      long e = c4 >> 2, r4 = c4 & 3;
      fl4 v = ((const fl4*)B)[e*16384 + o*4 + r4];
      us4 t; t[0]=f2bf(2.f*v[0]); t[1]=f2bf(2.f*v[1]);
             t[2]=f2bf(2.f*v[2]); t[3]=f2bf(2.f*v[3]);
      ((us4*)U)[j] = t;
    }
  }
}

// ---------------------------------------------------------------------------
// Kernel 2: gate_fused — barrier-free K-loop. grid 512 (BM=16), 256 thr.
// Wave w accumulates K-chunk [w*1024, +1024) with DIRECT global bf16x8 frag
// loads (no LDS staging): a = Xbf[(brow+r16)*4096 + k + kh*8] etc. Then one
// LDS reduce across the 4 waves, softmax gate, weighted-h write (bf16).
// ---------------------------------------------------------------------------
__global__ __launch_bounds__(256, 2) void gate_fused(
    const unsigned short* __restrict__ Xbf,
    const unsigned short* __restrict__ AG,
    unsigned short* __restrict__ HW)
{
  __shared__ float part[4][16][148];   // 148 = 144 + 4 pad (bank spread)

  int tid = threadIdx.x;
  int lane = tid & 63;
  int w = tid >> 6;
  long brow = (long)blockIdx.x * 16;
  int r16 = lane & 15, kh = lane >> 4;

  f32x4 acc[9];
#pragma unroll
  for (int i = 0; i < 9; ++i) acc[i] = (f32x4){0.f,0.f,0.f,0.f};

  const long kw = (long)w * 1024;
  const unsigned short* xp = Xbf + (brow + r16)*4096 + kw + kh*8;
  const unsigned short* gp = AG + (long)r16*4096 + kw + kh*8;

#pragma unroll 2
  for (int ks = 0; ks < 32; ++ks) {
    long k = (long)ks * 32;
    bf16x8 a = *(const bf16x8*)(xp + k);
#pragma unroll
    for (int c = 0; c < 9; ++c) {
      bf16x8 b = *(const bf16x8*)(gp + (long)c*16*4096 + k);
      acc[c] = __builtin_amdgcn_mfma_f32_16x16x32_bf16(a, b, acc[c], 0, 0, 0);
    }
  }

  // write per-wave partials (C/D: col=lane&15, row=(lane>>4)*4+j)
  int rg = lane >> 4;
#pragma unroll
  for (int c = 0; c < 9; ++c)
#pragma unroll
    for (int j = 0; j < 4; ++j)
      part[w][rg*4 + j][c*16 + r16] = acc[c][j];
  __syncthreads();

  // reduce 4 waves + softmax + weighted write. thread = (row r, 8-col slab q)
  {
    int r = tid >> 4;          // 0..15
    int q = tid & 15;          // 0..15 -> h cols q*8..q*8+7
    float lg[8];
#pragma unroll
    for (int e = 0; e < 8; ++e)
      lg[e] = part[0][r][e] + part[1][r][e] + part[2][r][e] + part[3][r][e];
    float mx = lg[0];
#pragma unroll
    for (int e = 1; e < 8; ++e) mx = fmaxf(mx, lg[e]);
    float ex[8]; float s = 0.f;
#pragma unroll
    for (int e = 0; e < 8; ++e) { ex[e] = __expf(lg[e] - mx); s += ex[e]; }
    float rt = ex[q >> 1] / s;          // expert = (q*8+j)>>4 == q>>1 for j<8
    int c0 = 8 + q*8;
    bf16x8 o;
#pragma unroll
    for (int j = 0; j < 8; ++j) {
      float hv = part[0][r][c0+j] + part[1][r][c0+j]
               + part[2][r][c0+j] + part[3][r][c0+j];
      o[j] = (short)f2bf(hv * rt);
    }
    *(bf16x8*)&HW[(brow + r)*128 + q*8] = o;
  }
}

// ---------------------------------------------------------------------------
// Kernel 3: 256x256 8-phase GEMM (unchanged schedule, verified r8: 0 bank
// conflicts, 987 TF) + XCD-aware bijective blockIdx swizzle (nwg=512%8==0).
// ---------------------------------------------------------------------------
#define NKT 66

struct Op { const unsigned short* a; const unsigned short* b; long lda, ldb, k0; };

__device__ __forceinline__ Op getop(int kt,
    const unsigned short* X, const unsigned short* W,
    const unsigned short* HW, const unsigned short* U) {
  Op o;
  if (kt < 64) { o.a = X;  o.b = W; o.lda = 4096; o.ldb = 4096; o.k0 = (long)kt*64; }
  else         { o.a = HW; o.b = U; o.lda = 128;  o.ldb = 128;  o.k0 = (long)(kt-64)*64; }
  return o;
}

__device__ __forceinline__ void stA(const unsigned short* src, long ld, long k0,
                                    long brow, char* dst, int mh, int t) {
  int l = t & 63, w = t >> 6;
  int kc = ((l & 7) ^ (l >> 3)) << 3;     // pre-swizzled source chunk (involution)
#pragma unroll
  for (int i = 0; i < 2; ++i) {
    long grow = (long)i*128 + mh*64 + w*8 + (l>>3);
    gload16(src + (brow + grow)*ld + k0 + kc,
            dst + mh*8192 + i*16384 + (long)t*16);
  }
}
__device__ __forceinline__ void stB(const unsigned short* src, long ld, long k0,
                                    long bcol, char* dst, int nh, int t) {
  int l = t & 63, w = t >> 6;
  int kc = ((l & 7) ^ (l >> 3)) << 3;
#pragma unroll
  for (int i = 0; i < 2; ++i) {
    long grow = ((long)i*2 + (w>>2))*64 + nh*32 + (w&3)*8 + (l>>3);
    gload16(src + (bcol + grow)*ld + k0 + kc,
            dst + i*16384 + (w>>2)*8192 + nh*4096 + ((long)(w&3)*64 + l)*16);
  }
}

__device__ __forceinline__ bf16x8 frag(const char* buf, int row, int ks, int kh, int l7) {
  int slot = (ks*4 + kh) ^ l7;            // swizzled read (matches staging)
  return *(const bf16x8*)(buf + (long)row*128 + slot*16);
}

__global__ __launch_bounds__(512, 2) void gemm8(
    const unsigned short* __restrict__ Xbf,
    const unsigned short* __restrict__ Wbf,
    const unsigned short* __restrict__ HW,
    const unsigned short* __restrict__ U,
    const float* __restrict__ bias,
    float* __restrict__ out)
{
  __shared__ char lds[131072];            // A: [buf][256][64], B at +65536

  int tid = threadIdx.x;
  int lane = tid & 63;
  int w = tid >> 6;
  int wr = w >> 2, wc = w & 3;
  int r16 = lane & 15, kh = lane >> 4, l7 = lane & 7;

  // T1: XCD-aware bijective swizzle. HW round-robins blockIdx%8 across XCDs;
  // remap so each XCD owns 64 consecutive logical tiles (512%8==0 -> bijective).
  int bid = ((blockIdx.x & 7) << 6) + (blockIdx.x >> 3);
  long brow = (long)(bid >> 4) * 256;
  long bcol = (long)(bid & 15) * 256;

  f32x4 acc[2][2][4][2];
#pragma unroll
  for (int mh = 0; mh < 2; ++mh)
#pragma unroll
    for (int nh = 0; nh < 2; ++nh)
#pragma unroll
      for (int m = 0; m < 4; ++m)
#pragma unroll
        for (int n = 0; n < 2; ++n) acc[mh][nh][m][n] = (f32x4){0.f,0.f,0.f,0.f};

  char* A0b = lds;
  char* B0b = lds + 65536;

  {
    Op o0 = getop(0, Xbf, Wbf, HW, U);
    Op o1 = getop(1, Xbf, Wbf, HW, U);
    stA(o0.a, o0.lda, o0.k0, brow, A0b, 0, tid);
    stB(o0.b, o0.ldb, o0.k0, bcol, B0b, 0, tid);
    stB(o0.b, o0.ldb, o0.k0, bcol, B0b, 1, tid);
    stA(o0.a, o0.lda, o0.k0, brow, A0b, 1, tid);
    stA(o1.a, o1.lda, o1.k0, brow, A0b + 32768, 0, tid);
    stB(o1.b, o1.ldb, o1.k0, bcol, B0b + 32768, 0, tid);
    stB(o1.b, o1.ldb, o1.k0, bcol, B0b + 32768, 1, tid);
    VMCNT6();
    BAR();
  }

  bf16x8 a[4][2], b0[2][2], b1[2][2];

  for (int kt = 0; kt < NKT; ++kt) {
    const char* rA = A0b + (kt & 1) * 32768;
    const char* rB = B0b + (kt & 1) * 32768;
    char* wA1 = A0b + ((kt + 1) & 1) * 32768;
    char* wA2 = A0b + (kt & 1) * 32768;
    char* wB2 = B0b + (kt & 1) * 32768;
    Op o1 = getop(kt + 1 < NKT ? kt + 1 : 0, Xbf, Wbf, HW, U);
    Op o2 = getop(kt + 2 < NKT ? kt + 2 : 0, Xbf, Wbf, HW, U);

    // P1: read A(mh=0)+B(nh=0); stage A1(kt+1); Q(0,0)
#pragma unroll
    for (int m = 0; m < 4; ++m)
#pragma unroll
      for (int ks = 0; ks < 2; ++ks)
        a[m][ks] = frag(rA, wr*128 + m*16 + r16, ks, kh, l7);
#pragma unroll
    for (int n = 0; n < 2; ++n)
#pragma unroll
      for (int ks = 0; ks < 2; ++ks)
        b0[n][ks] = frag(rB, wc*64 + n*16 + r16, ks, kh, l7);
    if (kt + 1 < NKT) stA(o1.a, o1.lda, o1.k0, brow, wA1, 1, tid);
    BAR();
    __builtin_amdgcn_s_setprio(1);
#pragma unroll
    for (int m = 0; m < 4; ++m)
#pragma unroll
      for (int n = 0; n < 2; ++n)
#pragma unroll
        for (int ks = 0; ks < 2; ++ks)
          acc[0][0][m][n] = __builtin_amdgcn_mfma_f32_16x16x32_bf16(
              a[m][ks], b0[n][ks], acc[0][0][m][n], 0, 0, 0);
    __builtin_amdgcn_s_setprio(0);
    BAR();

    // P2: read B(nh=1); stage A0(kt+2); Q(0,1)
#pragma unroll
    for (int n = 0; n < 2; ++n)
#pragma unroll
      for (int ks = 0; ks < 2; ++ks)
        b1[n][ks] = frag(rB, wc*64 + 32 + n*16 + r16, ks, kh, l7);
    if (kt + 2 < NKT) stA(o2.a, o2.lda, o2.k0, brow, wA2, 0, tid);
    BAR();
    __builtin_amdgcn_s_setprio(1);
#pragma unroll
    for (int m = 0; m < 4; ++m)
#pragma unroll
      for (int n = 0; n < 2; ++n)
#pragma unroll
        for (int ks = 0; ks < 2; ++ks)
          acc[0][1][m][n] = __builtin_amdgcn_mfma_f32_16x16x32_bf16(
              a[m][ks], b1[n][ks], acc[0][1][m][n], 0, 0, 0);
    __builtin_amdgcn_s_setprio(0);
    BAR();

    // P3: read A(mh=1); stage B0(kt+2); Q(1,1)
#pragma unroll
    for (int m = 0; m < 4; ++m)
#pragma unroll
      for (int ks = 0; ks < 2; ++ks)
        a[m][ks] = frag(rA, wr*128 + 64 + m*16 + r16, ks, kh, l7);
    if (kt + 2 < NKT) stB(o2.b, o2.ldb, o2.k0, bcol, wB2, 0, tid);
    BAR();
    __builtin_amdgcn_s_setprio(1);
#pragma unroll
    for (int m = 0; m < 4; ++m)
#pragma unroll
      for (int n = 0; n < 2; ++n)
#pragma unroll
        for (int ks = 0; ks < 2; ++ks)
          acc[1][1][m][n] = __builtin_amdgcn_mfma_f32_16x16x32_bf16(
              a[m][ks], b1[n][ks], acc[1][1][m][n], 0, 0, 0);
    __builtin_amdgcn_s_setprio(0);
    BAR();

    // P4: stage B1(kt+2); counted vmcnt; Q(1,0)
    if (kt + 2 < NKT) {
      stB(o2.b, o2.ldb, o2.k0, bcol, wB2, 1, tid);
      VMCNT6();
    } else if (kt + 1 < NKT) {
      VMCNT0();
    }
    BAR();
    __builtin_amdgcn_s_setprio(1);
#pragma unroll
    for (int m = 0; m < 4; ++m)
#pragma unroll
      for (int n = 0; n < 2; ++n)
#pragma unroll
        for (int ks = 0; ks < 2; ++ks)
          acc[1][0][m][n] = __builtin_amdgcn_mfma_f32_16x16x32_bf16(
              a[m][ks], b0[n][ks], acc[1][0][m][n], 0, 0, 0);
    __builtin_amdgcn_s_setprio(0);
    BAR();
  }

  int rg = lane >> 4;
#pragma unroll
  for (int mh = 0; mh < 2; ++mh)
#pragma unroll
    for (int nh = 0; nh < 2; ++nh)
#pragma unroll
      for (int n = 0; n < 2; ++n) {
        long col = bcol + wc*64 + nh*32 + n*16 + r16;
        float bv = bias[col];
#pragma unroll
        for (int m = 0; m < 4; ++m) {
          long row0 = brow + wr*128 + mh*64 + m*16 + rg*4;
#pragma unroll
          for (int j = 0; j < 4; ++j)
            out[(row0 + j)*4096 + col] = acc[mh][nh][m][n][j] + bv;
        }
      }
}

// ---------------------------------------------------------------------------
extern "C" void kernel_launch(void* const* d_in, const int* in_sizes, int n_in,
                              void* d_out, int out_size, void* d_ws, size_t ws_size,
                              hipStream_t stream) {
  (void)in_sizes; (void)n_in; (void)out_size; (void)ws_size;
  const float* x  = (const float*)d_in[0];
  const float* Wb = (const float*)d_in[1];
  const float* bb = (const float*)d_in[2];
  const float* Wg = (const float*)d_in[3];
  const float* A  = (const float*)d_in[4];
  const float* B  = (const float*)d_in[5];
  float* out = (float*)d_out;
  char* ws = (char*)d_ws;

  unsigned short* Xbf = (unsigned short*)(ws + WS_XBF);
  unsigned short* Wbf = (unsigned short*)(ws + WS_WBF);
  unsigned short* AG  = (unsigned short*)(ws + WS_AG);
  unsigned short* U   = (unsigned short*)(ws + WS_U);
  unsigned short* HW  = (unsigned short*)(ws + WS_HW);

  hipLaunchKernelGGL(prep_kernel, dim3(2048), dim3(256), 0, stream,
                     x, Wb, Wg, A, B, Xbf, Wbf, AG, U);
  hipLaunchKernelGGL(gate_fused, dim3(512), dim3(256), 0, stream,
                     Xbf, AG, HW);
  hipLaunchKernelGGL(gemm8, dim3(512), dim3(512), 0, stream,
                     Xbf, Wbf, HW, U, bb, out);
}

// Round 10
// 571.681 us; speedup vs baseline: 1.0100x; 1.0100x over previous
//
#include <hip/hip_runtime.h>
#include <hip/hip_bf16.h>

// ---------------------------------------------------------------------------
// LinearMoLoraLayer: out = x@W_base^T + b_base + 2.0 * sum_e route[e]*(x@A_e^T)@B_e^T
// R10: gemm8 hot-loop addressing rewrite — per-thread staging pointers
// precomputed, +128B/tile increment, main loop peeled from LoRA tail.
// Schedule/swizzle/vmcnt ledger identical to r8/r9 (verified: 0 conflicts).
// ---------------------------------------------------------------------------

typedef __attribute__((ext_vector_type(8))) short  bf16x8;
typedef __attribute__((ext_vector_type(4))) float  f32x4;
typedef __attribute__((ext_vector_type(4))) unsigned short us4;
typedef __attribute__((ext_vector_type(4))) float  fl4;

__device__ __forceinline__ unsigned short f2bf(float f) {
  unsigned int u = __float_as_uint(f);
  u += 0x7FFFu + ((u >> 16) & 1u);
  return (unsigned short)(u >> 16);
}
__device__ __forceinline__ void gload16(const void* g, void* l) {
  __builtin_amdgcn_global_load_lds(
      (const __attribute__((address_space(1))) unsigned int*)g,
      (__attribute__((address_space(3))) unsigned int*)l, 16, 0, 0);
}

#define BAR() do { asm volatile("" ::: "memory"); \
                   __builtin_amdgcn_s_barrier();  \
                   asm volatile("" ::: "memory"); } while (0)
#define VMCNT6() asm volatile("s_waitcnt vmcnt(6)" ::: "memory")
#define VMCNT0() asm volatile("s_waitcnt vmcnt(0)" ::: "memory")

// ---- workspace layout (bytes) ---------------------------------------------
#define WS_XBF 0u           // [8192][4096] bf16
#define WS_WBF 67108864u    // [4096][4096] bf16
#define WS_AG  100663296u   // [144][4096]  bf16 (rows 0..7 Wg, 8..135 A, 136..143 zero)
#define WS_U   101842944u   // [4096][128]  bf16 (U[o][e*16+r] = 2*B[e][o][r])
#define WS_HW  102891520u   // [8192][128]  bf16 (hw = h*route)

// ---------------------------------------------------------------------------
// Kernel 1: conversions/packing (unchanged, verified)
// ---------------------------------------------------------------------------
__global__ __launch_bounds__(256) void prep_kernel(
    const float* __restrict__ x, const float* __restrict__ Wb,
    const float* __restrict__ Wg, const float* __restrict__ A,
    const float* __restrict__ B,
    unsigned short* __restrict__ Xbf, unsigned short* __restrict__ Wbf,
    unsigned short* __restrict__ AG, unsigned short* __restrict__ U)
{
  const long N0 = 8388608;
  const long N1 = N0 + 4194304;
  const long N2 = N1 + 139264;
  const long N3 = N2 + 8192;
  const long N4 = N3 + 131072;
  long i = (long)blockIdx.x * blockDim.x + threadIdx.x;
  long stride = (long)gridDim.x * blockDim.x;
  for (; i < N4; i += stride) {
    if (i < N1) {
      const float* s; unsigned short* d; long j;
      if (i < N0) { s = x;  d = Xbf; j = i; }
      else        { s = Wb; d = Wbf; j = i - N0; }
      fl4 v = ((const fl4*)s)[j];
      us4 o; o[0]=f2bf(v[0]); o[1]=f2bf(v[1]); o[2]=f2bf(v[2]); o[3]=f2bf(v[3]);
      ((us4*)d)[j] = o;
    } else if (i < N2) {
      long j = i - N1;
      fl4 v = (j < 8192) ? ((const fl4*)Wg)[j] : ((const fl4*)A)[j - 8192];
      us4 o; o[0]=f2bf(v[0]); o[1]=f2bf(v[1]); o[2]=f2bf(v[2]); o[3]=f2bf(v[3]);
      ((us4*)AG)[j] = o;
    } else if (i < N3) {
      long j = i - N2;
      us4 z = (us4)0;
      ((us4*)(AG + 136*4096))[j] = z;
    } else {
      long j = i - N3;
      long o = j >> 5;
      long c4 = j & 31;
      long e = c4 >> 2, r4 = c4 & 3;
      fl4 v = ((const fl4*)B)[e*16384 + o*4 + r4];
      us4 t; t[0]=f2bf(2.f*v[0]); t[1]=f2bf(2.f*v[1]);
             t[2]=f2bf(2.f*v[2]); t[3]=f2bf(2.f*v[3]);
      ((us4*)U)[j] = t;
    }
  }
}

// ---------------------------------------------------------------------------
// Kernel 2: gate_fused (unchanged from r9 — passed; barrier-free K-loop)
// ---------------------------------------------------------------------------
__global__ __launch_bounds__(256, 2) void gate_fused(
    const unsigned short* __restrict__ Xbf,
    const unsigned short* __restrict__ AG,
    unsigned short* __restrict__ HW)
{
  __shared__ float part[4][16][148];

  int tid = threadIdx.x;
  int lane = tid & 63;
  int w = tid >> 6;
  long brow = (long)blockIdx.x * 16;
  int r16 = lane & 15, kh = lane >> 4;

  f32x4 acc[9];
#pragma unroll
  for (int i = 0; i < 9; ++i) acc[i] = (f32x4){0.f,0.f,0.f,0.f};

  const long kw = (long)w * 1024;
  const unsigned short* xp = Xbf + (brow + r16)*4096 + kw + kh*8;
  const unsigned short* gp = AG + (long)r16*4096 + kw + kh*8;

#pragma unroll 2
  for (int ks = 0; ks < 32; ++ks) {
    long k = (long)ks * 32;
    bf16x8 a = *(const bf16x8*)(xp + k);
#pragma unroll
    for (int c = 0; c < 9; ++c) {
      bf16x8 b = *(const bf16x8*)(gp + (long)c*16*4096 + k);
      acc[c] = __builtin_amdgcn_mfma_f32_16x16x32_bf16(a, b, acc[c], 0, 0, 0);
    }
  }

  int rg = lane >> 4;
#pragma unroll
  for (int c = 0; c < 9; ++c)
#pragma unroll
    for (int j = 0; j < 4; ++j)
      part[w][rg*4 + j][c*16 + r16] = acc[c][j];
  __syncthreads();

  {
    int r = tid >> 4;
    int q = tid & 15;
    float lg[8];
#pragma unroll
    for (int e = 0; e < 8; ++e)
      lg[e] = part[0][r][e] + part[1][r][e] + part[2][r][e] + part[3][r][e];
    float mx = lg[0];
#pragma unroll
    for (int e = 1; e < 8; ++e) mx = fmaxf(mx, lg[e]);
    float ex[8]; float s = 0.f;
#pragma unroll
    for (int e = 0; e < 8; ++e) { ex[e] = __expf(lg[e] - mx); s += ex[e]; }
    float rt = ex[q >> 1] / s;
    int c0 = 8 + q*8;
    bf16x8 o;
#pragma unroll
    for (int j = 0; j < 8; ++j) {
      float hv = part[0][r][c0+j] + part[1][r][c0+j]
               + part[2][r][c0+j] + part[3][r][c0+j];
      o[j] = (short)f2bf(hv * rt);
    }
    *(bf16x8*)&HW[(brow + r)*128 + q*8] = o;
  }
}

// ---------------------------------------------------------------------------
// Kernel 3: 256x256 8-phase GEMM. Main loop kt=[0,62): pointer-increment
// staging (base + kt*128B). Peeled kt=62..65: original generic code (LoRA
// handoff + drain), verified r8/r9.
// ---------------------------------------------------------------------------
#define NKT 66

struct Op { const unsigned short* a; const unsigned short* b; long lda, ldb, k0; };

__device__ __forceinline__ Op getop(int kt,
    const unsigned short* X, const unsigned short* W,
    const unsigned short* HW, const unsigned short* U) {
  Op o;
  if (kt < 64) { o.a = X;  o.b = W; o.lda = 4096; o.ldb = 4096; o.k0 = (long)kt*64; }
  else         { o.a = HW; o.b = U; o.lda = 128;  o.ldb = 128;  o.k0 = (long)(kt-64)*64; }
  return o;
}

__device__ __forceinline__ void stA(const unsigned short* src, long ld, long k0,
                                    long brow, char* dst, int mh, int t) {
  int l = t & 63, w = t >> 6;
  int kc = ((l & 7) ^ (l >> 3)) << 3;
#pragma unroll
  for (int i = 0; i < 2; ++i) {
    long grow = (long)i*128 + mh*64 + w*8 + (l>>3);
    gload16(src + (brow + grow)*ld + k0 + kc,
            dst + mh*8192 + i*16384 + (long)t*16);
  }
}
__device__ __forceinline__ void stB(const unsigned short* src, long ld, long k0,
                                    long bcol, char* dst, int nh, int t) {
  int l = t & 63, w = t >> 6;
  int kc = ((l & 7) ^ (l >> 3)) << 3;
#pragma unroll
  for (int i = 0; i < 2; ++i) {
    long grow = ((long)i*2 + (w>>2))*64 + nh*32 + (w&3)*8 + (l>>3);
    gload16(src + (bcol + grow)*ld + k0 + kc,
            dst + i*16384 + (w>>2)*8192 + nh*4096 + ((long)(w&3)*64 + l)*16);
  }
}

__device__ __forceinline__ bf16x8 frag(const char* buf, int row, int ks, int kh, int l7) {
  int slot = (ks*4 + kh) ^ l7;
  return *(const bf16x8*)(buf + (long)row*128 + slot*16);
}

__global__ __launch_bounds__(512, 2) void gemm8(
    const unsigned short* __restrict__ Xbf,
    const unsigned short* __restrict__ Wbf,
    const unsigned short* __restrict__ HW,
    const unsigned short* __restrict__ U,
    const float* __restrict__ bias,
    float* __restrict__ out)
{
  __shared__ char lds[131072];            // A: [buf][256][64], B at +65536

  int tid = threadIdx.x;
  int lane = tid & 63;
  int w = tid >> 6;
  int wr = w >> 2, wc = w & 3;
  int r16 = lane & 15, kh = lane >> 4, l7 = lane & 7;

  // T1 XCD swizzle (bijective, 512%8==0)
  int bid = ((blockIdx.x & 7) << 6) + (blockIdx.x >> 3);
  long brow = (long)(bid >> 4) * 256;
  long bcol = (long)(bid & 15) * 256;

  f32x4 acc[2][2][4][2];
#pragma unroll
  for (int mh = 0; mh < 2; ++mh)
#pragma unroll
    for (int nh = 0; nh < 2; ++nh)
#pragma unroll
      for (int m = 0; m < 4; ++m)
#pragma unroll
        for (int n = 0; n < 2; ++n) acc[mh][nh][m][n] = (f32x4){0.f,0.f,0.f,0.f};

  // ---- precomputed per-thread staging addresses (main X/W loop) ----
  int l8 = lane >> 3, k8 = lane & 7;
  long kcB = (long)((k8 ^ l8) << 4);                  // swizzled byte offset in 128B k-block
  long wrow = (long)(w*8 + l8);
  const char* gA00 = (const char*)Xbf + (brow +   0 + wrow)*8192 + kcB;
  const char* gA01 = (const char*)Xbf + (brow + 128 + wrow)*8192 + kcB;
  const char* gA10 = (const char*)Xbf + (brow +  64 + wrow)*8192 + kcB;
  const char* gA11 = (const char*)Xbf + (brow + 192 + wrow)*8192 + kcB;
  long brB = (long)((w>>2)*64 + (w&3)*8 + l8);
  const char* gB00 = (const char*)Wbf + (bcol + brB +   0)*8192 + kcB;
  const char* gB01 = (const char*)Wbf + (bcol + brB + 128)*8192 + kcB;
  const char* gB10 = (const char*)Wbf + (bcol + brB +  32)*8192 + kcB;
  const char* gB11 = (const char*)Wbf + (bcol + brB + 160)*8192 + kcB;
  // LDS dest offsets (match stA/stB formulas)
  const int ldsA00 = tid*16;
  const int ldsA01 = 16384 + tid*16;
  const int ldsA10 = 8192  + tid*16;
  const int ldsA11 = 24576 + tid*16;
  const int bB = 65536 + (w>>2)*8192 + ((w&3)*64 + lane)*16;
  const int ldsB00 = bB;
  const int ldsB01 = bB + 16384;
  const int ldsB10 = bB + 4096;
  const int ldsB11 = bB + 20480;

  char* A0b = lds;
  char* B0b = lds + 65536;

  // Prologue: tile0 (4 halves) + tile1 {A0,B0,B1}; same issue order as r8/r9
  {
    gload16(gA00,       lds + ldsA00); gload16(gA01,       lds + ldsA01);
    gload16(gB00,       lds + ldsB00); gload16(gB01,       lds + ldsB01);
    gload16(gB10,       lds + ldsB10); gload16(gB11,       lds + ldsB11);
    gload16(gA10,       lds + ldsA10); gload16(gA11,       lds + ldsA11);
    gload16(gA00 + 128, lds + ldsA00 + 32768); gload16(gA01 + 128, lds + ldsA01 + 32768);
    gload16(gB00 + 128, lds + ldsB00 + 32768); gload16(gB01 + 128, lds + ldsB01 + 32768);
    gload16(gB10 + 128, lds + ldsB10 + 32768); gload16(gB11 + 128, lds + ldsB11 + 32768);
    VMCNT6();
    BAR();
  }

  bf16x8 a[4][2], b0[2][2], b1[2][2];

  // ---- main loop: kt in [0,62), all staging targets are X/W tiles ----
  for (int kt = 0; kt < 62; ++kt) {
    const int pc = (kt & 1) << 15;
    const int pn = ((kt + 1) & 1) << 15;
    const char* rA = lds + pc;
    const char* rB = lds + 65536 + pc;
    const long kb1 = (long)(kt + 1) * 128;
    const long kb2 = (long)(kt + 2) * 128;

    // P1: read A(mh=0)+B(nh=0); stage A1(kt+1); Q(0,0)
#pragma unroll
    for (int m = 0; m < 4; ++m)
#pragma unroll
      for (int ks = 0; ks < 2; ++ks)
        a[m][ks] = frag(rA, wr*128 + m*16 + r16, ks, kh, l7);
#pragma unroll
    for (int n = 0; n < 2; ++n)
#pragma unroll
      for (int ks = 0; ks < 2; ++ks)
        b0[n][ks] = frag(rB, wc*64 + n*16 + r16, ks, kh, l7);
    gload16(gA10 + kb1, lds + ldsA10 + pn);
    gload16(gA11 + kb1, lds + ldsA11 + pn);
    BAR();
    __builtin_amdgcn_s_setprio(1);
#pragma unroll
    for (int m = 0; m < 4; ++m)
#pragma unroll
      for (int n = 0; n < 2; ++n)
#pragma unroll
        for (int ks = 0; ks < 2; ++ks)
          acc[0][0][m][n] = __builtin_amdgcn_mfma_f32_16x16x32_bf16(
              a[m][ks], b0[n][ks], acc[0][0][m][n], 0, 0, 0);
    __builtin_amdgcn_s_setprio(0);
    BAR();

    // P2: read B(nh=1); stage A0(kt+2); Q(0,1)
#pragma unroll
    for (int n = 0; n < 2; ++n)
#pragma unroll
      for (int ks = 0; ks < 2; ++ks)
        b1[n][ks] = frag(rB, wc*64 + 32 + n*16 + r16, ks, kh, l7);
    gload16(gA00 + kb2, lds + ldsA00 + pc);
    gload16(gA01 + kb2, lds + ldsA01 + pc);
    BAR();
    __builtin_amdgcn_s_setprio(1);
#pragma unroll
    for (int m = 0; m < 4; ++m)
#pragma unroll
      for (int n = 0; n < 2; ++n)
#pragma unroll
        for (int ks = 0; ks < 2; ++ks)
          acc[0][1][m][n] = __builtin_amdgcn_mfma_f32_16x16x32_bf16(
              a[m][ks], b1[n][ks], acc[0][1][m][n], 0, 0, 0);
    __builtin_amdgcn_s_setprio(0);
    BAR();

    // P3: read A(mh=1); stage B0(kt+2); Q(1,1)
#pragma unroll
    for (int m = 0; m < 4; ++m)
#pragma unroll
      for (int ks = 0; ks < 2; ++ks)
        a[m][ks] = frag(rA, wr*128 + 64 + m*16 + r16, ks, kh, l7);
    gload16(gB00 + kb2, lds + ldsB00 + pc);
    gload16(gB01 + kb2, lds + ldsB01 + pc);
    BAR();
    __builtin_amdgcn_s_setprio(1);
#pragma unroll
    for (int m = 0; m < 4; ++m)
#pragma unroll
      for (int n = 0; n < 2; ++n)
#pragma unroll
        for (int ks = 0; ks < 2; ++ks)
          acc[1][1][m][n] = __builtin_amdgcn_mfma_f32_16x16x32_bf16(
              a[m][ks], b1[n][ks], acc[1][1][m][n], 0, 0, 0);
    __builtin_amdgcn_s_setprio(0);
    BAR();

    // P4: stage B1(kt+2); counted vmcnt; Q(1,0)
    gload16(gB10 + kb2, lds + ldsB10 + pc);
    gload16(gB11 + kb2, lds + ldsB11 + pc);
    VMCNT6();
    BAR();
    __builtin_amdgcn_s_setprio(1);
#pragma unroll
    for (int m = 0; m < 4; ++m)
#pragma unroll
      for (int n = 0; n < 2; ++n)
#pragma unroll
        for (int ks = 0; ks < 2; ++ks)
          acc[1][0][m][n] = __builtin_amdgcn_mfma_f32_16x16x32_bf16(
              a[m][ks], b0[n][ks], acc[1][0][m][n], 0, 0, 0);
    __builtin_amdgcn_s_setprio(0);
    BAR();
  }

  // ---- peeled tail: kt=62..65 (generic, verified r8/r9) ----
  for (int kt = 62; kt < NKT; ++kt) {
    const char* rA = A0b + (kt & 1) * 32768;
    const char* rB = B0b + (kt & 1) * 32768;
    char* wA1 = A0b + ((kt + 1) & 1) * 32768;
    char* wA2 = A0b + (kt & 1) * 32768;
    char* wB2 = B0b + (kt & 1) * 32768;
    Op o1 = getop(kt + 1 < NKT ? kt + 1 : 0, Xbf, Wbf, HW, U);
    Op o2 = getop(kt + 2 < NKT ? kt + 2 : 0, Xbf, Wbf, HW, U);

    // P1
#pragma unroll
    for (int m = 0; m < 4; ++m)
#pragma unroll
      for (int ks = 0; ks < 2; ++ks)
        a[m][ks] = frag(rA, wr*128 + m*16 + r16, ks, kh, l7);
#pragma unroll
    for (int n = 0; n < 2; ++n)
#pragma unroll
      for (int ks = 0; ks < 2; ++ks)
        b0[n][ks] = frag(rB, wc*64 + n*16 + r16, ks, kh, l7);
    if (kt + 1 < NKT) stA(o1.a, o1.lda, o1.k0, brow, wA1, 1, tid);
    BAR();
    __builtin_amdgcn_s_setprio(1);
#pragma unroll
    for (int m = 0; m < 4; ++m)
#pragma unroll
      for (int n = 0; n < 2; ++n)
#pragma unroll
        for (int ks = 0; ks < 2; ++ks)
          acc[0][0][m][n] = __builtin_amdgcn_mfma_f32_16x16x32_bf16(
              a[m][ks], b0[n][ks], acc[0][0][m][n], 0, 0, 0);
    __builtin_amdgcn_s_setprio(0);
    BAR();

    // P2
#pragma unroll
    for (int n = 0; n < 2; ++n)
#pragma unroll
      for (int ks = 0; ks < 2; ++ks)
        b1[n][ks] = frag(rB, wc*64 + 32 + n*16 + r16, ks, kh, l7);
    if (kt + 2 < NKT) stA(o2.a, o2.lda, o2.k0, brow, wA2, 0, tid);
    BAR();
    __builtin_amdgcn_s_setprio(1);
#pragma unroll
    for (int m = 0; m < 4; ++m)
#pragma unroll
      for (int n = 0; n < 2; ++n)
#pragma unroll
        for (int ks = 0; ks < 2; ++ks)
          acc[0][1][m][n] = __builtin_amdgcn_mfma_f32_16x16x32_bf16(
              a[m][ks], b1[n][ks], acc[0][1][m][n], 0, 0, 0);
    __builtin_amdgcn_s_setprio(0);
    BAR();

    // P3
#pragma unroll
    for (int m = 0; m < 4; ++m)
#pragma unroll
      for (int ks = 0; ks < 2; ++ks)
        a[m][ks] = frag(rA, wr*128 + 64 + m*16 + r16, ks, kh, l7);
    if (kt + 2 < NKT) stB(o2.b, o2.ldb, o2.k0, bcol, wB2, 0, tid);
    BAR();
    __builtin_amdgcn_s_setprio(1);
#pragma unroll
    for (int m = 0; m < 4; ++m)
#pragma unroll
      for (int n = 0; n < 2; ++n)
#pragma unroll
        for (int ks = 0; ks < 2; ++ks)
          acc[1][1][m][n] = __builtin_amdgcn_mfma_f32_16x16x32_bf16(
              a[m][ks], b1[n][ks], acc[1][1][m][n], 0, 0, 0);
    __builtin_amdgcn_s_setprio(0);
    BAR();

    // P4
    if (kt + 2 < NKT) {
      stB(o2.b, o2.ldb, o2.k0, bcol, wB2, 1, tid);
      VMCNT6();
    } else if (kt + 1 < NKT) {
      VMCNT0();
    }
    BAR();
    __builtin_amdgcn_s_setprio(1);
#pragma unroll
    for (int m = 0; m < 4; ++m)
#pragma unroll
      for (int n = 0; n < 2; ++n)
#pragma unroll
        for (int ks = 0; ks < 2; ++ks)
          acc[1][0][m][n] = __builtin_amdgcn_mfma_f32_16x16x32_bf16(
              a[m][ks], b0[n][ks], acc[1][0][m][n], 0, 0, 0);
    __builtin_amdgcn_s_setprio(0);
    BAR();
  }

  // Epilogue
  int rg = lane >> 4;
#pragma unroll
  for (int mh = 0; mh < 2; ++mh)
#pragma unroll
    for (int nh = 0; nh < 2; ++nh)
#pragma unroll
      for (int n = 0; n < 2; ++n) {
        long col = bcol + wc*64 + nh*32 + n*16 + r16;
        float bv = bias[col];
#pragma unroll
        for (int m = 0; m < 4; ++m) {
          long row0 = brow + wr*128 + mh*64 + m*16 + rg*4;
#pragma unroll
          for (int j = 0; j < 4; ++j)
            out[(row0 + j)*4096 + col] = acc[mh][nh][m][n][j] + bv;
        }
      }
}

// ---------------------------------------------------------------------------
extern "C" void kernel_launch(void* const* d_in, const int* in_sizes, int n_in,
                              void* d_out, int out_size, void* d_ws, size_t ws_size,
                              hipStream_t stream) {
  (void)in_sizes; (void)n_in; (void)out_size; (void)ws_size;
  const float* x  = (const float*)d_in[0];
  const float* Wb = (const float*)d_in[1];
  const float* bb = (const float*)d_in[2];
  const float* Wg = (const float*)d_in[3];
  const float* A  = (const float*)d_in[4];
  const float* B  = (const float*)d_in[5];
  float* out = (float*)d_out;
  char* ws = (char*)d_ws;

  unsigned short* Xbf = (unsigned short*)(ws + WS_XBF);
  unsigned short* Wbf = (unsigned short*)(ws + WS_WBF);
  unsigned short* AG  = (unsigned short*)(ws + WS_AG);
  unsigned short* U   = (unsigned short*)(ws + WS_U);
  unsigned short* HW  = (unsigned short*)(ws + WS_HW);

  hipLaunchKernelGGL(prep_kernel, dim3(2048), dim3(256), 0, stream,
                     x, Wb, Wg, A, B, Xbf, Wbf, AG, U);
  hipLaunchKernelGGL(gate_fused, dim3(512), dim3(256), 0, stream,
                     Xbf, AG, HW);
  hipLaunchKernelGGL(gemm8, dim3(512), dim3(512), 0, stream,
                     Xbf, Wbf, HW, U, bb, out);
}